// Round 11
// baseline (975.562 us; speedup 1.0000x reference)
//
#include <hip/hip_runtime.h>
#include <hip/hip_bf16.h>

#define HH 64
#define XDIM 896
#define FF 512
#define LL 6
#define CC 40
#define CBSZ 512          // nodes per coarse bucket
#define SLACK 10240       // slots per bucket region
#define NPB 128           // nodes per fused block
#define HPAD 72           // LDS row stride (shorts): 144B -> conflict-free ds_read_b128

typedef __bf16 bf16x8 __attribute__((ext_vector_type(8)));
typedef float f32x4 __attribute__((ext_vector_type(4)));

__device__ __forceinline__ unsigned short f2bf(float f){
  union{float f; unsigned int u;} v; v.f=f; unsigned int u=v.u;
  return (unsigned short)((u + 0x7fffu + ((u>>16)&1u))>>16);
}
__device__ __forceinline__ float u2f(unsigned u){
  union{unsigned u; float f;} v; v.u=u; return v.f;
}

// ---- fused prep: [0,256) edge-partition | [256,256+WB) wfrag | rest xcast ----
struct PrepP {
  const float* x; const int* ei;
  unsigned short* X; unsigned short* linA; unsigned short* linB;
  int* bcur; unsigned* tmp;
  const float* W[7]; unsigned short* dst[7];
  int nt[7], nc[7], off[8];
  int N, E, CH, NB, WB;
};

__global__ void __launch_bounds__(256) k_prep(PrepP P){
  __shared__ int hist[256];
  __shared__ int run[256];
  int t=threadIdx.x, b=blockIdx.x;
  if (b < 256){
    int E=P.E;
    int lo=b*P.CH, hi=lo+P.CH; if (hi>E) hi=E;
    for (int i=t;i<P.NB;i+=256) hist[i]=0;
    __syncthreads();
    for (int i=lo+t;i<hi;i+=256) atomicAdd(&hist[P.ei[E+i]>>9], 1);
    __syncthreads();
    for (int i=t;i<P.NB;i+=256) run[i]=i*SLACK+atomicAdd(&P.bcur[i], hist[i]);
    __syncthreads();
    for (int i=lo+t;i<hi;i+=256){
      int r=P.ei[i], c=P.ei[E+i];
      int pos=atomicAdd(&run[c>>9],1);
      P.tmp[pos]=((unsigned)r<<9)|(unsigned)(c&(CBSZ-1));
    }
  } else if (b < 256+P.WB){
    int idx=(b-256)*256+t;
    if (idx < P.off[7]){
      int seg=0;
      while (idx>=P.off[seg+1]) ++seg;
      int li=idx-P.off[seg];
      int j=li&7, ln=(li>>3)&63, rem2=li>>9;
      int ntile=P.nt[seg], ncols=P.nc[seg];
      int nt=rem2%ntile, kb=rem2/ntile;
      int k=kb*32+(ln>>4)*8+j;
      int c=nt*16+(ln&15);
      float v=(c<ncols)? P.W[seg][(size_t)k*ncols+c] : 0.f;
      P.dst[seg][li]=f2bf(v);
    }
  } else {
    int i=(b-256-P.WB)*256+t;
    if (i<32){
      ((unsigned*)(P.linA+(size_t)P.N*64))[i]=0u;
      ((unsigned*)(P.linB+(size_t)P.N*64))[i]=0u;
    }
    int total=P.N*(FF/4);
    if (i<total){
      int row=i/(FF/4), c4=(i%(FF/4))*4;
      float4 v=*(const float4*)(P.x+(size_t)row*FF+c4);
      ushort4 o; o.x=f2bf(v.x); o.y=f2bf(v.y); o.z=f2bf(v.z); o.w=f2bf(v.w);
      *(ushort4*)(P.X+(size_t)row*XDIM+c4)=o;
    }
  }
}

// ---- per-bucket: LDS count + scan -> offs/dinv; LDS-cursor scatter -> esrc ----
__global__ void __launch_bounds__(1024) k_build(const unsigned* __restrict__ tmp,
                                                const int* __restrict__ bcur,
                                                int* __restrict__ offsS, int* __restrict__ offsE,
                                                float* __restrict__ dinv,
                                                int* __restrict__ esrc, int N){
  __shared__ int cnt[CBSZ];
  __shared__ int run[CBSZ];
  int t=threadIdx.x, b=blockIdx.x;
  int n0=b*CBSZ;
  int nloc=N-n0; if (nloc>CBSZ) nloc=CBSZ;
  int wbase=b*SLACK;
  int wend=wbase + bcur[b];
  if (t<CBSZ) cnt[t]=0;
  __syncthreads();
  for (int i=wbase+t; i<wend; i+=1024) atomicAdd(&cnt[tmp[i]&(CBSZ-1u)],1);
  __syncthreads();
  int v = (t<CBSZ)? cnt[t] : 0;
  if (t<CBSZ) run[t]=v;
  __syncthreads();
  for (int o=1;o<CBSZ;o<<=1){
    int xx = (t<CBSZ && t>=o)? run[t-o] : 0;
    __syncthreads();
    if (t<CBSZ) run[t]+=xx;
    __syncthreads();
  }
  if (t<nloc){
    int s = wbase + (run[t]-v);
    offsS[n0+t]=s;
    offsE[n0+t]=s+v;
    dinv[n0+t]=rsqrtf((float)(v+1));
    run[t]=s;
  }
  __syncthreads();
  for (int i=wbase+t; i<wend; i+=1024){
    unsigned vv=tmp[i];
    int pos=atomicAdd(&run[vv&(CBSZ-1u)],1);
    esrc[pos]=(int)(vv>>9);
  }
}

// ---- layer-0 gemm: linA[N,64] = (X[:, :512] @ Wf) * dinv[row] ----
__global__ void __launch_bounds__(256) k_gemm(const unsigned short* __restrict__ X,
                                              const unsigned short* __restrict__ Wf,
                                              const float* __restrict__ dinv,
                                              unsigned short* __restrict__ lin,
                                              int N, int nkb){
  int lane = threadIdx.x & 63, wid = threadIdx.x >> 6;
  long row0 = (long)blockIdx.x*128 + wid*32;
  int arow = lane & 15, kgrp = lane >> 4;
  long r0 = row0 + arow;      if (r0 > (long)N-1) r0 = N-1;
  long r1 = row0 + 16 + arow; if (r1 > (long)N-1) r1 = N-1;
  const unsigned short* ap0 = X + (size_t)r0*XDIM + kgrp*8;
  const unsigned short* ap1 = X + (size_t)r1*XDIM + kgrp*8;
  const unsigned short* bptr = Wf + lane*8;
  f32x4 acc00={0.f,0.f,0.f,0.f}, acc01=acc00, acc02=acc00, acc03=acc00;
  f32x4 acc10=acc00, acc11=acc00, acc12=acc00, acc13=acc00;
  for (int kb=0; kb<nkb; ++kb){
    bf16x8 a0 = *(const bf16x8*)(ap0 + (size_t)kb*32);
    bf16x8 a1 = *(const bf16x8*)(ap1 + (size_t)kb*32);
    const unsigned short* bp = bptr + (size_t)kb*2048;
    bf16x8 b0=*(const bf16x8*)bp, b1=*(const bf16x8*)(bp+512),
           b2=*(const bf16x8*)(bp+1024), b3=*(const bf16x8*)(bp+1536);
    acc00=__builtin_amdgcn_mfma_f32_16x16x32_bf16(a0,b0,acc00,0,0,0);
    acc10=__builtin_amdgcn_mfma_f32_16x16x32_bf16(a1,b0,acc10,0,0,0);
    acc01=__builtin_amdgcn_mfma_f32_16x16x32_bf16(a0,b1,acc01,0,0,0);
    acc11=__builtin_amdgcn_mfma_f32_16x16x32_bf16(a1,b1,acc11,0,0,0);
    acc02=__builtin_amdgcn_mfma_f32_16x16x32_bf16(a0,b2,acc02,0,0,0);
    acc12=__builtin_amdgcn_mfma_f32_16x16x32_bf16(a1,b2,acc12,0,0,0);
    acc03=__builtin_amdgcn_mfma_f32_16x16x32_bf16(a0,b3,acc03,0,0,0);
    acc13=__builtin_amdgcn_mfma_f32_16x16x32_bf16(a1,b3,acc13,0,0,0);
  }
  for (int j=0;j<4;++j){
    long rr = row0 + kgrp*4 + j;
    if (rr < N){
      float dv = dinv[rr];
      unsigned short* lp = lin + (size_t)rr*64 + arow;
      lp[0]  = f2bf(acc00[j]*dv);
      lp[16] = f2bf(acc01[j]*dv);
      lp[32] = f2bf(acc02[j]*dv);
      lp[48] = f2bf(acc03[j]*dv);
    }
    long rr1 = rr + 16;
    if (rr1 < N){
      float dv = dinv[rr1];
      unsigned short* lp = lin + (size_t)rr1*64 + arow;
      lp[0]  = f2bf(acc10[j]*dv);
      lp[16] = f2bf(acc11[j]*dv);
      lp[32] = f2bf(acc12[j]*dv);
      lp[48] = f2bf(acc13[j]*dv);
    }
  }
}

// ---- R5-proven agg body: uint2 gathers, sub=lane>>4 (0..3), fq=lane&15 ----
#define AGG_BODY(lqp, n_, a0,a1,a2,a3) \
  { \
    int s = offsS[n_], e = offsE[n_]; \
    int base = s; \
    for (; base + 32 <= e; base += 32){ \
      _Pragma("unroll") \
      for (int k=0;k<8;++k){ \
        int sx = esrc[base + 4*k + sub]; \
        uint2 v = *(const uint2*)(lqp + (size_t)sx*64); \
        a0 += u2f(v.x<<16); a1 += u2f(v.x&0xffff0000u); \
        a2 += u2f(v.y<<16); a3 += u2f(v.y&0xffff0000u); \
      } \
    } \
    if (base < e){ \
      int rem = e - base; \
      if (rem > 16){ \
        _Pragma("unroll") \
        for (int k=0;k<8;++k){ \
          int idx = 4*k + sub; \
          int sx = esrc[base + idx]; \
          sx = (idx < rem) ? sx : (int)N; \
          uint2 v = *(const uint2*)(lqp + (size_t)sx*64); \
          a0 += u2f(v.x<<16); a1 += u2f(v.x&0xffff0000u); \
          a2 += u2f(v.y<<16); a3 += u2f(v.y&0xffff0000u); \
        } \
      } else { \
        _Pragma("unroll") \
        for (int k=0;k<4;++k){ \
          int idx = 4*k + sub; \
          int sx = esrc[base + idx]; \
          sx = (idx < rem) ? sx : (int)N; \
          uint2 v = *(const uint2*)(lqp + (size_t)sx*64); \
          a0 += u2f(v.x<<16); a1 += u2f(v.x&0xffff0000u); \
          a2 += u2f(v.y<<16); a3 += u2f(v.y&0xffff0000u); \
        } \
      } \
    } \
    a0 += __shfl_xor(a0,16,64); a0 += __shfl_xor(a0,32,64); \
    a1 += __shfl_xor(a1,16,64); a1 += __shfl_xor(a1,32,64); \
    a2 += __shfl_xor(a2,16,64); a2 += __shfl_xor(a2,32,64); \
    a3 += __shfl_xor(a3,16,64); a3 += __shfl_xor(a3,32,64); \
    uint2 vs = *(const uint2*)(lqp + (size_t)n_*64); \
    a0 += u2f(vs.x<<16); a1 += u2f(vs.x&0xffff0000u); \
    a2 += u2f(vs.y<<16); a3 += u2f(vs.y&0xffff0000u); \
  }

// ---- fused: agg_i (128 nodes -> LDS + X) then gemm_{i+1} (128 rows, H from LDS) ----
__global__ void __launch_bounds__(256) k_fused(const unsigned short* __restrict__ linR,
                                               unsigned short* __restrict__ linW,
                                               const int* __restrict__ offsS,
                                               const int* __restrict__ offsE,
                                               const int* __restrict__ esrc,
                                               const float* __restrict__ dinv,
                                               const float* __restrict__ bias,
                                               unsigned short* __restrict__ X,
                                               const unsigned short* __restrict__ Wf,
                                               int colbase, int nkb, int N){
  __shared__ unsigned short sh[NPB*HPAD];
  int t=threadIdx.x, lane=t&63, wid=t>>6;
  int nbase = blockIdx.x*NPB;
  int sub = lane>>4, fq = lane&15;
  {
    const unsigned short* lq = linR + fq*4;
    for (int it=0; it<32; ++it){
      int n = nbase + wid*32 + it;
      if (n >= N) break;
      float a0=0.f, a1=0.f, a2=0.f, a3=0.f;
      AGG_BODY(lq, n, a0,a1,a2,a3)
      float dv = dinv[n];
      float4 b4 = *(const float4*)(bias + fq*4);
      float h0 = fmaxf(a0*dv + b4.x, 0.f);
      float h1 = fmaxf(a1*dv + b4.y, 0.f);
      float h2 = fmaxf(a2*dv + b4.z, 0.f);
      float h3 = fmaxf(a3*dv + b4.w, 0.f);
      if (sub == 0){
        ushort4 o; o.x=f2bf(h0); o.y=f2bf(h1); o.z=f2bf(h2); o.w=f2bf(h3);
        *(ushort4*)(&sh[(n-nbase)*HPAD + fq*4]) = o;
        *(ushort4*)(X + (size_t)n*XDIM + colbase + fq*4) = o;
      }
    }
  }
  __syncthreads();
  {
    int arow = lane & 15, kgrp = lane >> 4;
    int kbh = nkb - 2;
    long row0 = (long)nbase + wid*32;
    long r0 = row0 + arow;      if (r0 > (long)N-1) r0 = N-1;
    long r1 = row0 + 16 + arow; if (r1 > (long)N-1) r1 = N-1;
    const unsigned short* ap0 = X + (size_t)r0*XDIM + kgrp*8;
    const unsigned short* ap1 = X + (size_t)r1*XDIM + kgrp*8;
    int l0 = (int)(r0 - nbase)*HPAD + kgrp*8;
    int l1 = (int)(r1 - nbase)*HPAD + kgrp*8;
    const unsigned short* bptr = Wf + lane*8;
    f32x4 acc00={0.f,0.f,0.f,0.f}, acc01=acc00, acc02=acc00, acc03=acc00;
    f32x4 acc10=acc00, acc11=acc00, acc12=acc00, acc13=acc00;
    for (int kb=0; kb<nkb; ++kb){
      bf16x8 a0, a1;
      if (kb < kbh){
        a0 = *(const bf16x8*)(ap0 + (size_t)kb*32);
        a1 = *(const bf16x8*)(ap1 + (size_t)kb*32);
      } else {
        int c = (kb - kbh)*32;
        a0 = *(const bf16x8*)(&sh[l0 + c]);
        a1 = *(const bf16x8*)(&sh[l1 + c]);
      }
      const unsigned short* bp = bptr + (size_t)kb*2048;
      bf16x8 b0=*(const bf16x8*)bp, b1=*(const bf16x8*)(bp+512),
             b2=*(const bf16x8*)(bp+1024), b3=*(const bf16x8*)(bp+1536);
      acc00=__builtin_amdgcn_mfma_f32_16x16x32_bf16(a0,b0,acc00,0,0,0);
      acc10=__builtin_amdgcn_mfma_f32_16x16x32_bf16(a1,b0,acc10,0,0,0);
      acc01=__builtin_amdgcn_mfma_f32_16x16x32_bf16(a0,b1,acc01,0,0,0);
      acc11=__builtin_amdgcn_mfma_f32_16x16x32_bf16(a1,b1,acc11,0,0,0);
      acc02=__builtin_amdgcn_mfma_f32_16x16x32_bf16(a0,b2,acc02,0,0,0);
      acc12=__builtin_amdgcn_mfma_f32_16x16x32_bf16(a1,b2,acc12,0,0,0);
      acc03=__builtin_amdgcn_mfma_f32_16x16x32_bf16(a0,b3,acc03,0,0,0);
      acc13=__builtin_amdgcn_mfma_f32_16x16x32_bf16(a1,b3,acc13,0,0,0);
    }
    for (int j=0;j<4;++j){
      long rr = row0 + kgrp*4 + j;
      if (rr < N){
        float dv = dinv[rr];
        unsigned short* lp = linW + (size_t)rr*64 + arow;
        lp[0]  = f2bf(acc00[j]*dv);
        lp[16] = f2bf(acc01[j]*dv);
        lp[32] = f2bf(acc02[j]*dv);
        lp[48] = f2bf(acc03[j]*dv);
      }
      long rr1 = rr + 16;
      if (rr1 < N){
        float dv = dinv[rr1];
        unsigned short* lp = linW + (size_t)rr1*64 + arow;
        lp[0]  = f2bf(acc10[j]*dv);
        lp[16] = f2bf(acc11[j]*dv);
        lp[32] = f2bf(acc12[j]*dv);
        lp[48] = f2bf(acc13[j]*dv);
      }
    }
  }
}

// ---- fused final: agg_5 (LDS only, no X write) + JK-linear + log_softmax ----
__global__ void __launch_bounds__(256) k_ffinal(const unsigned short* __restrict__ linR,
                                                const int* __restrict__ offsS,
                                                const int* __restrict__ offsE,
                                                const int* __restrict__ esrc,
                                                const float* __restrict__ dinv,
                                                const float* __restrict__ bias,
                                                const unsigned short* __restrict__ X,
                                                const unsigned short* __restrict__ Wf,
                                                const float* __restrict__ blin,
                                                float* __restrict__ out, int N){
  __shared__ unsigned short sh[NPB*HPAD];
  int t=threadIdx.x, lane=t&63, wid=t>>6;
  int nbase = blockIdx.x*NPB;
  int sub = lane>>4, fq = lane&15;
  {
    const unsigned short* lq = linR + fq*4;
    for (int it=0; it<32; ++it){
      int n = nbase + wid*32 + it;
      if (n >= N) break;
      float a0=0.f, a1=0.f, a2=0.f, a3=0.f;
      AGG_BODY(lq, n, a0,a1,a2,a3)
      float dv = dinv[n];
      float4 b4 = *(const float4*)(bias + fq*4);
      float h0 = fmaxf(a0*dv + b4.x, 0.f);
      float h1 = fmaxf(a1*dv + b4.y, 0.f);
      float h2 = fmaxf(a2*dv + b4.z, 0.f);
      float h3 = fmaxf(a3*dv + b4.w, 0.f);
      if (sub == 0){
        ushort4 o; o.x=f2bf(h0); o.y=f2bf(h1); o.z=f2bf(h2); o.w=f2bf(h3);
        *(ushort4*)(&sh[(n-nbase)*HPAD + fq*4]) = o;
      }
    }
  }
  __syncthreads();
  {
    int c0=lane&15, g=lane>>4;
    const int nkb = XDIM/32, kbh = nkb-2;
    for (int tt=0; tt<2; ++tt){
      long row0 = (long)nbase + tt*64 + wid*16;
      long r = row0+c0; if (r > (long)N-1) r = N-1;
      const unsigned short* aptr = X + (size_t)r*XDIM + g*8;
      int lr = (int)(r - nbase)*HPAD + g*8;
      const unsigned short* bptr = Wf + lane*8;
      f32x4 acc0={0.f,0.f,0.f,0.f}, acc1=acc0, acc2=acc0;
      for (int kb=0;kb<nkb;++kb){
        bf16x8 a;
        if (kb < kbh) a = *(const bf16x8*)(aptr+(size_t)kb*32);
        else          a = *(const bf16x8*)(&sh[lr + (kb-kbh)*32]);
        const unsigned short* bp = bptr + (size_t)kb*1536;
        bf16x8 b0=*(const bf16x8*)bp, b1=*(const bf16x8*)(bp+512), b2=*(const bf16x8*)(bp+1024);
        acc0=__builtin_amdgcn_mfma_f32_16x16x32_bf16(a,b0,acc0,0,0,0);
        acc1=__builtin_amdgcn_mfma_f32_16x16x32_bf16(a,b1,acc1,0,0,0);
        acc2=__builtin_amdgcn_mfma_f32_16x16x32_bf16(a,b2,acc2,0,0,0);
      }
      float bl0 = blin[c0], bl1 = blin[16+c0];
      bool v2ok = (c0 < 8);
      float bl2 = v2ok ? blin[32+c0] : 0.f;
      for (int j=0;j<4;++j){
        long rr = row0 + g*4 + j;
        float v0 = acc0[j]+bl0, v1 = acc1[j]+bl1;
        float v2 = v2ok ? (acc2[j]+bl2) : -1e30f;
        float m = fmaxf(fmaxf(v0,v1),v2);
        m = fmaxf(m, __shfl_xor(m,1,64));
        m = fmaxf(m, __shfl_xor(m,2,64));
        m = fmaxf(m, __shfl_xor(m,4,64));
        m = fmaxf(m, __shfl_xor(m,8,64));
        float sEx = expf(v0-m)+expf(v1-m)+(v2ok?expf(v2-m):0.f);
        sEx += __shfl_xor(sEx,1,64);
        sEx += __shfl_xor(sEx,2,64);
        sEx += __shfl_xor(sEx,4,64);
        sEx += __shfl_xor(sEx,8,64);
        float lse = m + logf(sEx);
        if (rr < N){
          out[(size_t)rr*CC + c0]      = v0 - lse;
          out[(size_t)rr*CC + 16 + c0] = v1 - lse;
          if (v2ok) out[(size_t)rr*CC + 32 + c0] = v2 - lse;
        }
      }
    }
  }
}

extern "C" void kernel_launch(void* const* d_in, const int* in_sizes, int n_in,
                              void* d_out, int out_size, void* d_ws, size_t ws_size,
                              hipStream_t stream){
  const float* x = (const float*)d_in[0];
  const int* ei = (const int*)d_in[1];
  const float* Wl[LL]; const float* bl[LL];
  for (int i=0;i<LL;i++){ Wl[i]=(const float*)d_in[2+2*i]; bl[i]=(const float*)d_in[3+2*i]; }
  const float* Wlin = (const float*)d_in[2+2*LL];
  const float* blin = (const float*)d_in[3+2*LL];
  float* out = (float*)d_out;
  const int N = in_sizes[0]/FF;
  const int E = in_sizes[1]/2;
  const int NB = (N+CBSZ-1)/CBSZ;

  char* p = (char*)d_ws;
  auto alloc = [&](size_t bb)->char*{ char* r=p; p += (bb+255)&~(size_t)255; return r; };
  unsigned short* X    = (unsigned short*)alloc((size_t)N*XDIM*2);
  unsigned short* linA = (unsigned short*)alloc((size_t)(N+1)*64*2);  // +1 zero row
  unsigned short* linB = (unsigned short*)alloc((size_t)(N+1)*64*2);
  unsigned* tmp = (unsigned*)linA;  // alias: tmp (NB*SLACK*4 ~ 8MB) dead before gemm0
  unsigned short* WfL[LL+1];
  for (int i=0;i<LL;i++){ int d=FF+HH*i; WfL[i]=(unsigned short*)alloc((size_t)d*64*2); }
  WfL[LL] = (unsigned short*)alloc((size_t)XDIM*48*2);
  float* dinv  = (float*)alloc((size_t)N*4);
  int* offsS   = (int*)alloc((size_t)N*4);
  int* offsE   = (int*)alloc((size_t)N*4);
  int* bcur    = (int*)alloc((size_t)NB*4);
  int* esrc    = (int*)alloc(((size_t)NB*SLACK+64)*4);  // +64 pad for masked tail reads

  PrepP P;
  P.x=x; P.ei=ei; P.X=X; P.linA=linA; P.linB=linB; P.bcur=bcur; P.tmp=tmp;
  int off=0;
  for (int i=0;i<LL;i++){
    P.W[i]=Wl[i]; P.dst[i]=WfL[i]; P.nt[i]=4; P.nc[i]=HH;
    P.off[i]=off; off += ((FF+HH*i)>>5)*4*512;
  }
  P.W[LL]=Wlin; P.dst[LL]=WfL[LL]; P.nt[LL]=3; P.nc[LL]=CC;
  P.off[LL]=off; off += (XDIM>>5)*3*512;
  P.off[LL+1]=off;
  P.N=N; P.E=E; P.CH=(E+255)/256; P.NB=NB; P.WB=(off+255)/256;
  int XB=(N*(FF/4)+255)/256;

  hipMemsetAsync(bcur, 0, (size_t)NB*4, stream);
  k_prep <<<256 + P.WB + XB, 256, 0, stream>>>(P);
  k_build<<<NB, 1024, 0, stream>>>(tmp, bcur, offsS, offsE, dinv, esrc, N);

  int fb = (N+NPB-1)/NPB;
  k_gemm<<<fb,256,0,stream>>>(X, WfL[0], dinv, linA, N, FF>>5);
  unsigned short* cur = linA;
  unsigned short* oth = linB;
  for (int i=0;i<LL-1;i++){
    k_fused<<<fb,256,0,stream>>>(cur, oth, offsS, offsE, esrc, dinv, bl[i],
                                 X, WfL[i+1], FF+HH*i, (FF+HH*(i+1))>>5, N);
    unsigned short* t2 = cur; cur = oth; oth = t2;
  }
  k_ffinal<<<fb,256,0,stream>>>(cur, offsS, offsE, esrc, dinv, bl[LL-1],
                                X, WfL[LL], blin, out, N);
}

// Round 12
// 774.831 us; speedup vs baseline: 1.2591x; 1.2591x over previous
//
#include <hip/hip_runtime.h>
#include <hip/hip_bf16.h>

#define HH 64
#define XDIM 896
#define FF 512
#define LL 6
#define CC 40
#define CBSZ 512          // nodes per coarse bucket
#define SLACK 10240       // slots per bucket region
#define NSEG 13

typedef __bf16 bf16x8 __attribute__((ext_vector_type(8)));
typedef float f32x4 __attribute__((ext_vector_type(4)));

__device__ __forceinline__ unsigned short f2bf(float f){
  union{float f; unsigned int u;} v; v.f=f; unsigned int u=v.u;
  return (unsigned short)((u + 0x7fffu + ((u>>16)&1u))>>16);
}
__device__ __forceinline__ float bf2f(unsigned short u){
  union{unsigned int u; float f;} v; v.u = ((unsigned int)u)<<16; return v.f;
}
__device__ __forceinline__ float u2f(unsigned u){
  union{unsigned u; float f;} v; v.u=u; return v.f;
}

// ---- fused prep: [0,256) edge-partition | [256,256+WB) wfrag | rest xcast ----
struct PrepP {
  const float* x; const int* ei;
  unsigned short* X; unsigned short* lin;
  int* bcur; unsigned* tmp;
  const float* W[NSEG]; unsigned short* dst[NSEG];
  int nt[NSEG], nc[NSEG], tst[NSEG], tbs[NSEG], kbase[NSEG];
  int off[NSEG+1];
  int N, E, CH, NB, WB;
};

__global__ void __launch_bounds__(256) k_prep(PrepP P){
  __shared__ int hist[256];
  __shared__ int run[256];
  int t=threadIdx.x, b=blockIdx.x;
  if (b < 256){
    int E=P.E;
    int lo=b*P.CH, hi=lo+P.CH; if (hi>E) hi=E;
    for (int i=t;i<P.NB;i+=256) hist[i]=0;
    __syncthreads();
    for (int i=lo+t;i<hi;i+=256) atomicAdd(&hist[P.ei[E+i]>>9], 1);
    __syncthreads();
    for (int i=t;i<P.NB;i+=256) run[i]=i*SLACK+atomicAdd(&P.bcur[i], hist[i]);
    __syncthreads();
    for (int i=lo+t;i<hi;i+=256){
      int r=P.ei[i], c=P.ei[E+i];
      int pos=atomicAdd(&run[c>>9],1);
      P.tmp[pos]=((unsigned)r<<9)|(unsigned)(c&(CBSZ-1));
    }
  } else if (b < 256+P.WB){
    int idx=(b-256)*256+t;
    if (idx < P.off[NSEG]){
      int seg=0;
      while (idx>=P.off[seg+1]) ++seg;
      int li=idx-P.off[seg];
      int j=li&7, ln=(li>>3)&63, rem2=li>>9;
      int ntile=P.nt[seg], ncols=P.nc[seg];
      int nt_=rem2%ntile, kb=rem2/ntile;
      int k=P.kbase[seg]+kb*32+(ln>>4)*8+j;
      int c=nt_*16+(ln&15);
      float v=(c<ncols)? P.W[seg][(size_t)k*ncols+c] : 0.f;
      int di = ((kb*P.tst[seg] + P.tbs[seg] + nt_)*64 + ln)*8 + j;
      P.dst[seg][di]=f2bf(v);
    }
  } else {
    int i=(b-256-P.WB)*256+t;
    if (i<32) ((unsigned*)(P.lin+(size_t)P.N*64))[i]=0u;
    int total=P.N*(FF/4);
    if (i<total){
      int row=i/(FF/4), c4=(i%(FF/4))*4;
      float4 v=*(const float4*)(P.x+(size_t)row*FF+c4);
      ushort4 o; o.x=f2bf(v.x); o.y=f2bf(v.y); o.z=f2bf(v.z); o.w=f2bf(v.w);
      *(ushort4*)(P.X+(size_t)row*XDIM+c4)=o;
    }
  }
}

// ---- per-bucket: LDS count + scan -> offs/dinv; LDS-cursor scatter -> esrc ----
__global__ void __launch_bounds__(1024) k_build(const unsigned* __restrict__ tmp,
                                                const int* __restrict__ bcur,
                                                int* __restrict__ offsS, int* __restrict__ offsE,
                                                float* __restrict__ dinv,
                                                int* __restrict__ esrc, int N){
  __shared__ int cnt[CBSZ];
  __shared__ int run[CBSZ];
  int t=threadIdx.x, b=blockIdx.x;
  int n0=b*CBSZ;
  int nloc=N-n0; if (nloc>CBSZ) nloc=CBSZ;
  int wbase=b*SLACK;
  int wend=wbase + bcur[b];
  if (t<CBSZ) cnt[t]=0;
  __syncthreads();
  for (int i=wbase+t; i<wend; i+=1024) atomicAdd(&cnt[tmp[i]&(CBSZ-1u)],1);
  __syncthreads();
  int v = (t<CBSZ)? cnt[t] : 0;
  if (t<CBSZ) run[t]=v;
  __syncthreads();
  for (int o=1;o<CBSZ;o<<=1){
    int xx = (t<CBSZ && t>=o)? run[t-o] : 0;
    __syncthreads();
    if (t<CBSZ) run[t]+=xx;
    __syncthreads();
  }
  if (t<nloc){
    int s = wbase + (run[t]-v);
    offsS[n0+t]=s;
    offsE[n0+t]=s+v;
    dinv[n0+t]=rsqrtf((float)(v+1));
    run[t]=s;
  }
  __syncthreads();
  for (int i=wbase+t; i<wend; i+=1024){
    unsigned vv=tmp[i];
    int pos=atomicAdd(&run[vv&(CBSZ-1u)],1);
    esrc[pos]=(int)(vv>>9);
  }
}

// ---- big pass: X[:, :512] x {W0..W5, Wlin} -> lin0 (dinv'd) + partials 1..5 + pF ----
struct GBP {
  const unsigned short* X; const unsigned short* WfBig;
  const float* dinv;
  unsigned short* pl[6];   // pl[0] = lin (dinv applied), 1..5 = raw bf16 partials
  float* pF;               // [N,40] fp32 logits partial
  int N;
};

__global__ void __launch_bounds__(256) k_gbig(GBP P){
  int t=threadIdx.x, lane=t&63, wid=t>>6;
  int wpair=wid>>1, whalf=wid&1;
  int tb = whalf ? 13 : 0;          // tiles [tb, tb+14); tile 13 computed twice, written by whalf==0
  long row0 = (long)blockIdx.x*64 + wpair*32;
  int arow=lane&15, kgrp=lane>>4;
  long r0=row0+arow;    if (r0>(long)P.N-1) r0=P.N-1;
  long r1=row0+16+arow; if (r1>(long)P.N-1) r1=P.N-1;
  const unsigned short* ap0 = P.X + (size_t)r0*XDIM + kgrp*8;
  const unsigned short* ap1 = P.X + (size_t)r1*XDIM + kgrp*8;
  const unsigned short* bbase = P.WfBig + (size_t)tb*512 + lane*8;
  f32x4 acc0[14], acc1[14];
  #pragma unroll
  for (int i=0;i<14;i++){ f32x4 z={0.f,0.f,0.f,0.f}; acc0[i]=z; acc1[i]=z; }
  for (int kb=0;kb<16;++kb){
    bf16x8 a0=*(const bf16x8*)(ap0+(size_t)kb*32);
    bf16x8 a1=*(const bf16x8*)(ap1+(size_t)kb*32);
    const unsigned short* bp = bbase + (size_t)kb*27*512;
    #pragma unroll
    for (int tt=0;tt<14;++tt){
      bf16x8 b=*(const bf16x8*)(bp + tt*512);
      acc0[tt]=__builtin_amdgcn_mfma_f32_16x16x32_bf16(a0,b,acc0[tt],0,0,0);
      acc1[tt]=__builtin_amdgcn_mfma_f32_16x16x32_bf16(a1,b,acc1[tt],0,0,0);
    }
  }
  #pragma unroll
  for (int tt=0;tt<14;++tt){
    int tg = tb+tt;
    if (whalf && tt==0) continue;   // tile 13 duplicate
    #pragma unroll
    for (int j=0;j<4;++j){
      long rr=row0+kgrp*4+j, rr1=rr+16;
      if (tg<24){
        int li=tg>>2, tloc=tg&3;
        if (rr<P.N){
          float s = (li==0) ? P.dinv[rr] : 1.f;
          P.pl[li][(size_t)rr*64 + tloc*16 + arow] = f2bf(acc0[tt][j]*s);
        }
        if (rr1<P.N){
          float s = (li==0) ? P.dinv[rr1] : 1.f;
          P.pl[li][(size_t)rr1*64 + tloc*16 + arow] = f2bf(acc1[tt][j]*s);
        }
      } else {
        int c=(tg-24)*16+arow;
        if (c<CC){
          if (rr<P.N)  P.pF[(size_t)rr*CC+c]=acc0[tt][j];
          if (rr1<P.N) P.pF[(size_t)rr1*CC+c]=acc1[tt][j];
        }
      }
    }
  }
}

// ---- layer-i gemm over H cols only: lin = dinv*(partial + X[:,512:512+64i] @ WfH) ----
__global__ void __launch_bounds__(256) k_gemmH(const unsigned short* __restrict__ X,
                                               const unsigned short* __restrict__ WfH,
                                               const unsigned short* __restrict__ part,
                                               const float* __restrict__ dinv,
                                               unsigned short* __restrict__ lin,
                                               int N, int nkb2){
  int lane = threadIdx.x & 63, wid = threadIdx.x >> 6;
  long row0 = (long)blockIdx.x*128 + wid*32;
  int arow = lane & 15, kgrp = lane >> 4;
  long r0 = row0 + arow;      if (r0 > (long)N-1) r0 = N-1;
  long r1 = row0 + 16 + arow; if (r1 > (long)N-1) r1 = N-1;
  const unsigned short* ap0 = X + (size_t)r0*XDIM + FF + kgrp*8;
  const unsigned short* ap1 = X + (size_t)r1*XDIM + FF + kgrp*8;
  const unsigned short* bptr = WfH + lane*8;
  f32x4 acc00={0.f,0.f,0.f,0.f}, acc01=acc00, acc02=acc00, acc03=acc00;
  f32x4 acc10=acc00, acc11=acc00, acc12=acc00, acc13=acc00;
  for (int kb=0; kb<nkb2; ++kb){
    bf16x8 a0 = *(const bf16x8*)(ap0 + (size_t)kb*32);
    bf16x8 a1 = *(const bf16x8*)(ap1 + (size_t)kb*32);
    const unsigned short* bp = bptr + (size_t)kb*2048;
    bf16x8 b0=*(const bf16x8*)bp, b1=*(const bf16x8*)(bp+512),
           b2=*(const bf16x8*)(bp+1024), b3=*(const bf16x8*)(bp+1536);
    acc00=__builtin_amdgcn_mfma_f32_16x16x32_bf16(a0,b0,acc00,0,0,0);
    acc10=__builtin_amdgcn_mfma_f32_16x16x32_bf16(a1,b0,acc10,0,0,0);
    acc01=__builtin_amdgcn_mfma_f32_16x16x32_bf16(a0,b1,acc01,0,0,0);
    acc11=__builtin_amdgcn_mfma_f32_16x16x32_bf16(a1,b1,acc11,0,0,0);
    acc02=__builtin_amdgcn_mfma_f32_16x16x32_bf16(a0,b2,acc02,0,0,0);
    acc12=__builtin_amdgcn_mfma_f32_16x16x32_bf16(a1,b2,acc12,0,0,0);
    acc03=__builtin_amdgcn_mfma_f32_16x16x32_bf16(a0,b3,acc03,0,0,0);
    acc13=__builtin_amdgcn_mfma_f32_16x16x32_bf16(a1,b3,acc13,0,0,0);
  }
  for (int j=0;j<4;++j){
    long rr = row0 + kgrp*4 + j;
    if (rr < N){
      float dv = dinv[rr];
      const unsigned short* pp = part + (size_t)rr*64 + arow;
      unsigned short* lp = lin + (size_t)rr*64 + arow;
      lp[0]  = f2bf((acc00[j]+bf2f(pp[0]))*dv);
      lp[16] = f2bf((acc01[j]+bf2f(pp[16]))*dv);
      lp[32] = f2bf((acc02[j]+bf2f(pp[32]))*dv);
      lp[48] = f2bf((acc03[j]+bf2f(pp[48]))*dv);
    }
    long rr1 = rr + 16;
    if (rr1 < N){
      float dv = dinv[rr1];
      const unsigned short* pp = part + (size_t)rr1*64 + arow;
      unsigned short* lp = lin + (size_t)rr1*64 + arow;
      lp[0]  = f2bf((acc10[j]+bf2f(pp[0]))*dv);
      lp[16] = f2bf((acc11[j]+bf2f(pp[16]))*dv);
      lp[32] = f2bf((acc12[j]+bf2f(pp[32]))*dv);
      lp[48] = f2bf((acc13[j]+bf2f(pp[48]))*dv);
    }
  }
}

// ---- aggregate (R5/R9-proven): 1 wave/node; lane=(sub 0..3, fq 0..15); uint2 gathers ----
__global__ void __launch_bounds__(256) k_agg(const unsigned short* __restrict__ lin,
                                             const int* __restrict__ offsS,
                                             const int* __restrict__ offsE,
                                             const int* __restrict__ esrc,
                                             const float* __restrict__ dinv,
                                             const float* __restrict__ bias,
                                             unsigned short* __restrict__ X,
                                             int colbase, int N){
  int lane = threadIdx.x & 63, wid = threadIdx.x >> 6;
  int n = blockIdx.x*4 + wid;
  if (n >= N) return;
  int sub = lane >> 4;
  int fq  = lane & 15;
  const unsigned short* lq = lin + fq*4;
  float a0=0.f, a1=0.f, a2=0.f, a3=0.f;
  int s = offsS[n], e = offsE[n];
  int base = s;
  for (; base + 32 <= e; base += 32){
    #pragma unroll
    for (int k=0;k<8;++k){
      int sx = esrc[base + 4*k + sub];
      uint2 v = *(const uint2*)(lq + (size_t)sx*64);
      a0 += u2f(v.x<<16); a1 += u2f(v.x&0xffff0000u);
      a2 += u2f(v.y<<16); a3 += u2f(v.y&0xffff0000u);
    }
  }
  if (base < e){
    int rem = e - base;
    if (rem > 16){
      #pragma unroll
      for (int k=0;k<8;++k){
        int idx = 4*k + sub;
        int sx = esrc[base + idx];
        sx = (idx < rem) ? sx : (int)N;
        uint2 v = *(const uint2*)(lq + (size_t)sx*64);
        a0 += u2f(v.x<<16); a1 += u2f(v.x&0xffff0000u);
        a2 += u2f(v.y<<16); a3 += u2f(v.y&0xffff0000u);
      }
    } else {
      #pragma unroll
      for (int k=0;k<4;++k){
        int idx = 4*k + sub;
        int sx = esrc[base + idx];
        sx = (idx < rem) ? sx : (int)N;
        uint2 v = *(const uint2*)(lq + (size_t)sx*64);
        a0 += u2f(v.x<<16); a1 += u2f(v.x&0xffff0000u);
        a2 += u2f(v.y<<16); a3 += u2f(v.y&0xffff0000u);
      }
    }
  }
  a0 += __shfl_xor(a0,16,64); a0 += __shfl_xor(a0,32,64);
  a1 += __shfl_xor(a1,16,64); a1 += __shfl_xor(a1,32,64);
  a2 += __shfl_xor(a2,16,64); a2 += __shfl_xor(a2,32,64);
  a3 += __shfl_xor(a3,16,64); a3 += __shfl_xor(a3,32,64);
  uint2 vs = *(const uint2*)(lq + (size_t)n*64);
  a0 += u2f(vs.x<<16); a1 += u2f(vs.x&0xffff0000u);
  a2 += u2f(vs.y<<16); a3 += u2f(vs.y&0xffff0000u);
  float dv = dinv[n];
  float4 b4 = *(const float4*)(bias + fq*4);
  float h0 = fmaxf(a0*dv + b4.x, 0.f);
  float h1 = fmaxf(a1*dv + b4.y, 0.f);
  float h2 = fmaxf(a2*dv + b4.z, 0.f);
  float h3 = fmaxf(a3*dv + b4.w, 0.f);
  if (sub == 0){
    ushort4 o; o.x=f2bf(h0); o.y=f2bf(h1); o.z=f2bf(h2); o.w=f2bf(h3);
    *(ushort4*)(X + (size_t)n*XDIM + colbase + fq*4) = o;
  }
}

// ---- final: logits = pF + X[:,512:896] @ WfLinH + blin, log_softmax ----
__global__ void __launch_bounds__(256) k_final(const unsigned short* __restrict__ X,
                                               const unsigned short* __restrict__ Wf,
                                               const float* __restrict__ pF,
                                               const float* __restrict__ blin,
                                               float* __restrict__ out, int N){
  int lane=threadIdx.x&63, wid=threadIdx.x>>6;
  long row0=(long)blockIdx.x*64 + wid*16;
  int c0=lane&15, g=lane>>4;
  long r=row0+c0; if (r > (long)N-1) r = N-1;
  const unsigned short* aptr = X + (size_t)r*XDIM + FF + g*8;
  const unsigned short* bptr = Wf + lane*8;
  f32x4 acc0={0.f,0.f,0.f,0.f}, acc1=acc0, acc2=acc0;
  const int nkb = (XDIM-FF)/32;  // 12
  for (int kb=0;kb<nkb;++kb){
    bf16x8 a=*(const bf16x8*)(aptr+(size_t)kb*32);
    const unsigned short* bp = bptr + (size_t)kb*1536;
    bf16x8 b0=*(const bf16x8*)bp, b1=*(const bf16x8*)(bp+512), b2=*(const bf16x8*)(bp+1024);
    acc0=__builtin_amdgcn_mfma_f32_16x16x32_bf16(a,b0,acc0,0,0,0);
    acc1=__builtin_amdgcn_mfma_f32_16x16x32_bf16(a,b1,acc1,0,0,0);
    acc2=__builtin_amdgcn_mfma_f32_16x16x32_bf16(a,b2,acc2,0,0,0);
  }
  float bl0 = blin[c0], bl1 = blin[16+c0];
  bool v2ok = (c0 < 8);
  float bl2 = v2ok ? blin[32+c0] : 0.f;
  for (int j=0;j<4;++j){
    long rr = row0 + g*4 + j;
    long rrc = rr < N ? rr : (long)N-1;
    const float* pp = pF + (size_t)rrc*CC;
    float v0 = acc0[j]+bl0+pp[c0], v1 = acc1[j]+bl1+pp[16+c0];
    float v2 = v2ok ? (acc2[j]+bl2+pp[32+c0]) : -1e30f;
    float m = fmaxf(fmaxf(v0,v1),v2);
    m = fmaxf(m, __shfl_xor(m,1,64));
    m = fmaxf(m, __shfl_xor(m,2,64));
    m = fmaxf(m, __shfl_xor(m,4,64));
    m = fmaxf(m, __shfl_xor(m,8,64));
    float sEx = expf(v0-m)+expf(v1-m)+(v2ok?expf(v2-m):0.f);
    sEx += __shfl_xor(sEx,1,64);
    sEx += __shfl_xor(sEx,2,64);
    sEx += __shfl_xor(sEx,4,64);
    sEx += __shfl_xor(sEx,8,64);
    float lse = m + logf(sEx);
    if (rr < N){
      out[(size_t)rr*CC + c0]      = v0 - lse;
      out[(size_t)rr*CC + 16 + c0] = v1 - lse;
      if (v2ok) out[(size_t)rr*CC + 32 + c0] = v2 - lse;
    }
  }
}

extern "C" void kernel_launch(void* const* d_in, const int* in_sizes, int n_in,
                              void* d_out, int out_size, void* d_ws, size_t ws_size,
                              hipStream_t stream){
  const float* x = (const float*)d_in[0];
  const int* ei = (const int*)d_in[1];
  const float* Wl[LL]; const float* bl[LL];
  for (int i=0;i<LL;i++){ Wl[i]=(const float*)d_in[2+2*i]; bl[i]=(const float*)d_in[3+2*i]; }
  const float* Wlin = (const float*)d_in[2+2*LL];
  const float* blin = (const float*)d_in[3+2*LL];
  float* out = (float*)d_out;
  const int N = in_sizes[0]/FF;
  const int E = in_sizes[1]/2;
  const int NB = (N+CBSZ-1)/CBSZ;

  char* p = (char*)d_ws;
  auto alloc = [&](size_t bb)->char*{ char* r=p; p += (bb+255)&~(size_t)255; return r; };
  unsigned short* X   = (unsigned short*)alloc((size_t)N*XDIM*2);
  unsigned short* lin = (unsigned short*)alloc((size_t)(N+1)*64*2);  // +1 zero row
  unsigned* tmp = (unsigned*)lin;  // alias: tmp dead before gbig writes lin
  unsigned short* WfBig  = (unsigned short*)alloc((size_t)16*27*512*2);
  unsigned short* WfH[LL];   // index 1..5
  for (int i=1;i<LL;i++) WfH[i]=(unsigned short*)alloc((size_t)(2*i)*4*512*2);
  unsigned short* WfLinH = (unsigned short*)alloc((size_t)12*3*512*2);
  unsigned short* part[LL];  // index 1..5
  for (int i=1;i<LL;i++) part[i]=(unsigned short*)alloc((size_t)N*64*2);
  float* pF    = (float*)alloc((size_t)N*CC*4);
  float* dinv  = (float*)alloc((size_t)N*4);
  int* offsS   = (int*)alloc((size_t)N*4);
  int* offsE   = (int*)alloc((size_t)N*4);
  int* bcur    = (int*)alloc((size_t)NB*4);
  int* esrc    = (int*)alloc(((size_t)NB*SLACK+64)*4);

  PrepP P;
  P.x=x; P.ei=ei; P.X=X; P.lin=lin; P.bcur=bcur; P.tmp=tmp;
  int off=0, sg=0;
  // big segments: 6 layer W prefixes + Wlin prefix -> WfBig [kb][27][512]
  for (int i=0;i<LL;i++){
    P.W[sg]=Wl[i]; P.dst[sg]=WfBig; P.nt[sg]=4; P.nc[sg]=HH;
    P.tst[sg]=27; P.tbs[sg]=4*i; P.kbase[sg]=0;
    P.off[sg]=off; off += 16*4*512; ++sg;
  }
  P.W[sg]=Wlin; P.dst[sg]=WfBig; P.nt[sg]=3; P.nc[sg]=CC;
  P.tst[sg]=27; P.tbs[sg]=24; P.kbase[sg]=0;
  P.off[sg]=off; off += 16*3*512; ++sg;
  // H segments for layers 1..5
  for (int i=1;i<LL;i++){
    P.W[sg]=Wl[i]; P.dst[sg]=WfH[i]; P.nt[sg]=4; P.nc[sg]=HH;
    P.tst[sg]=4; P.tbs[sg]=0; P.kbase[sg]=FF;
    P.off[sg]=off; off += (2*i)*4*512; ++sg;
  }
  // Wlin H segment
  P.W[sg]=Wlin; P.dst[sg]=WfLinH; P.nt[sg]=3; P.nc[sg]=CC;
  P.tst[sg]=3; P.tbs[sg]=0; P.kbase[sg]=FF;
  P.off[sg]=off; off += 12*3*512; ++sg;
  P.off[sg]=off;
  P.N=N; P.E=E; P.CH=(E+255)/256; P.NB=NB; P.WB=(off+255)/256;
  int XB=(N*(FF/4)+255)/256;

  hipMemsetAsync(bcur, 0, (size_t)NB*4, stream);
  k_prep <<<256 + P.WB + XB, 256, 0, stream>>>(P);
  k_build<<<NB, 1024, 0, stream>>>(tmp, bcur, offsS, offsE, dinv, esrc, N);

  GBP G;
  G.X=X; G.WfBig=WfBig; G.dinv=dinv;
  G.pl[0]=lin;
  for (int i=1;i<LL;i++) G.pl[i]=part[i];
  G.pF=pF; G.N=N;
  k_gbig<<<(N+63)/64, 256, 0, stream>>>(G);

  int gb = (N+127)/128;
  int ab = (N+3)/4;
  for (int i=0;i<LL;i++){
    if (i>0) k_gemmH<<<gb,256,0,stream>>>(X, WfH[i], part[i], dinv, lin, N, 2*i);
    k_agg<<<ab,256,0,stream>>>(lin, offsS, offsE, esrc, dinv, bl[i], X, FF+HH*i, N);
  }
  k_final<<<(N+63)/64,256,0,stream>>>(X, WfLinH, pF, blin, out, N);
}

// Round 13
// 641.330 us; speedup vs baseline: 1.5212x; 1.2082x over previous
//
#include <hip/hip_runtime.h>
#include <hip/hip_bf16.h>

#define HH 64
#define XDIM 896
#define FF 512
#define LL 6
#define CC 40
#define CBSZ 512          // nodes per coarse bucket
#define SLACK 10240       // slots per bucket region
#define NSEG 13

typedef __bf16 bf16x8 __attribute__((ext_vector_type(8)));
typedef float f32x4 __attribute__((ext_vector_type(4)));

__device__ __forceinline__ unsigned short f2bf(float f){
  union{float f; unsigned int u;} v; v.f=f; unsigned int u=v.u;
  return (unsigned short)((u + 0x7fffu + ((u>>16)&1u))>>16);
}
__device__ __forceinline__ float bf2f(unsigned short u){
  union{unsigned int u; float f;} v; v.u = ((unsigned int)u)<<16; return v.f;
}
__device__ __forceinline__ float u2f(unsigned u){
  union{unsigned u; float f;} v; v.u=u; return v.f;
}

// ---- fused prep: [0,256) edge-partition | [256,256+WB) wfrag | rest xcast ----
struct PrepP {
  const float* x; const int* ei;
  unsigned short* X; unsigned short* lin;
  int* bcur; unsigned* tmp;
  const float* W[NSEG]; unsigned short* dst[NSEG];
  int nt[NSEG], nc[NSEG], tst[NSEG], tbs[NSEG], kbase[NSEG];
  int off[NSEG+1];
  int N, E, CH, NB, WB;
};

__global__ void __launch_bounds__(256) k_prep(PrepP P){
  __shared__ int hist[256];
  __shared__ int run[256];
  int t=threadIdx.x, b=blockIdx.x;
  if (b < 256){
    int E=P.E;
    int lo=b*P.CH, hi=lo+P.CH; if (hi>E) hi=E;
    for (int i=t;i<P.NB;i+=256) hist[i]=0;
    __syncthreads();
    for (int i=lo+t;i<hi;i+=256) atomicAdd(&hist[P.ei[E+i]>>9], 1);
    __syncthreads();
    for (int i=t;i<P.NB;i+=256) run[i]=i*SLACK+atomicAdd(&P.bcur[i], hist[i]);
    __syncthreads();
    for (int i=lo+t;i<hi;i+=256){
      int r=P.ei[i], c=P.ei[E+i];
      int pos=atomicAdd(&run[c>>9],1);
      P.tmp[pos]=((unsigned)r<<9)|(unsigned)(c&(CBSZ-1));
    }
  } else if (b < 256+P.WB){
    int idx=(b-256)*256+t;
    if (idx < P.off[NSEG]){
      int seg=0;
      while (idx>=P.off[seg+1]) ++seg;
      int li=idx-P.off[seg];
      int j=li&7, ln=(li>>3)&63, rem2=li>>9;
      int ntile=P.nt[seg], ncols=P.nc[seg];
      int nt_=rem2%ntile, kb=rem2/ntile;
      int k=P.kbase[seg]+kb*32+(ln>>4)*8+j;
      int c=nt_*16+(ln&15);
      float v=(c<ncols)? P.W[seg][(size_t)k*ncols+c] : 0.f;
      int di = ((kb*P.tst[seg] + P.tbs[seg] + nt_)*64 + ln)*8 + j;
      P.dst[seg][di]=f2bf(v);
    }
  } else {
    int i=(b-256-P.WB)*256+t;
    if (i<32) ((unsigned*)(P.lin+(size_t)P.N*64))[i]=0u;
    int total=P.N*(FF/4);
    if (i<total){
      int row=i/(FF/4), c4=(i%(FF/4))*4;
      float4 v=*(const float4*)(P.x+(size_t)row*FF+c4);
      ushort4 o; o.x=f2bf(v.x); o.y=f2bf(v.y); o.z=f2bf(v.z); o.w=f2bf(v.w);
      *(ushort4*)(P.X+(size_t)row*XDIM+c4)=o;
    }
  }
}

// ---- per-bucket: LDS count + scan -> offs/dinv; LDS-cursor scatter -> esrc ----
__global__ void __launch_bounds__(1024) k_build(const unsigned* __restrict__ tmp,
                                                const int* __restrict__ bcur,
                                                int* __restrict__ offsS, int* __restrict__ offsE,
                                                float* __restrict__ dinv,
                                                int* __restrict__ esrc, int N){
  __shared__ int cnt[CBSZ];
  __shared__ int run[CBSZ];
  int t=threadIdx.x, b=blockIdx.x;
  int n0=b*CBSZ;
  int nloc=N-n0; if (nloc>CBSZ) nloc=CBSZ;
  int wbase=b*SLACK;
  int wend=wbase + bcur[b];
  if (t<CBSZ) cnt[t]=0;
  __syncthreads();
  for (int i=wbase+t; i<wend; i+=1024) atomicAdd(&cnt[tmp[i]&(CBSZ-1u)],1);
  __syncthreads();
  int v = (t<CBSZ)? cnt[t] : 0;
  if (t<CBSZ) run[t]=v;
  __syncthreads();
  for (int o=1;o<CBSZ;o<<=1){
    int xx = (t<CBSZ && t>=o)? run[t-o] : 0;
    __syncthreads();
    if (t<CBSZ) run[t]+=xx;
    __syncthreads();
  }
  if (t<nloc){
    int s = wbase + (run[t]-v);
    offsS[n0+t]=s;
    offsE[n0+t]=s+v;
    dinv[n0+t]=rsqrtf((float)(v+1));
    run[t]=s;
  }
  __syncthreads();
  for (int i=wbase+t; i<wend; i+=1024){
    unsigned vv=tmp[i];
    int pos=atomicAdd(&run[vv&(CBSZ-1u)],1);
    esrc[pos]=(int)(vv>>9);
  }
}

// ---- big pass v2: 16 rows x 14 tiles per wave (no spill) ----
// block = 32 rows; waves (half=row strip, tq=tile group 0->tiles[0,14), 1->[13,27), tile13 dup)
struct GBP {
  const unsigned short* X; const unsigned short* WfBig;
  const float* dinv;
  unsigned short* pl[6];   // pl[0] = lin (dinv applied), 1..5 = raw bf16 partials
  float* pF;               // [N,40] fp32 logits partial
  int N;
};

__global__ void __launch_bounds__(256) k_gbig(GBP P){
  int t=threadIdx.x, lane=t&63, wid=t>>6;
  int half = wid & 1;          // row strip within the 32-row block
  int tq   = wid >> 1;         // tile group
  int tb   = tq ? 13 : 0;      // tiles [tb, tb+14); tile 13 duplicated, written by tq==0
  long row0 = (long)blockIdx.x*32 + half*16;
  int arow=lane&15, kgrp=lane>>4;
  long r=row0+arow; if (r>(long)P.N-1) r=P.N-1;
  const unsigned short* ap = P.X + (size_t)r*XDIM + kgrp*8;
  const unsigned short* bbase = P.WfBig + (size_t)tb*512 + lane*8;
  f32x4 acc[14];
  #pragma unroll
  for (int i=0;i<14;i++){ f32x4 z={0.f,0.f,0.f,0.f}; acc[i]=z; }
  for (int kb=0;kb<16;++kb){
    bf16x8 a=*(const bf16x8*)(ap+(size_t)kb*32);
    const unsigned short* bp = bbase + (size_t)kb*27*512;
    #pragma unroll
    for (int tt=0;tt<14;++tt){
      bf16x8 b=*(const bf16x8*)(bp + tt*512);
      acc[tt]=__builtin_amdgcn_mfma_f32_16x16x32_bf16(a,b,acc[tt],0,0,0);
    }
  }
  #pragma unroll
  for (int tt=0;tt<14;++tt){
    if (tq && tt==0) continue;   // tile 13 duplicate
    int tg = tb+tt;
    #pragma unroll
    for (int j=0;j<4;++j){
      long rr=row0+kgrp*4+j;
      if (rr >= P.N) continue;
      if (tg<24){
        int li=tg>>2, tloc=tg&3;
        float s = (li==0) ? P.dinv[rr] : 1.f;
        P.pl[li][(size_t)rr*64 + tloc*16 + arow] = f2bf(acc[tt][j]*s);
      } else {
        int c=(tg-24)*16+arow;
        if (c<CC) P.pF[(size_t)rr*CC+c]=acc[tt][j];
      }
    }
  }
}

// ---- layer-i gemm over H cols only: lin = dinv*(partial + X[:,512:512+64i] @ WfH) ----
__global__ void __launch_bounds__(256) k_gemmH(const unsigned short* __restrict__ X,
                                               const unsigned short* __restrict__ WfH,
                                               const unsigned short* __restrict__ part,
                                               const float* __restrict__ dinv,
                                               unsigned short* __restrict__ lin,
                                               int N, int nkb2){
  int lane = threadIdx.x & 63, wid = threadIdx.x >> 6;
  long row0 = (long)blockIdx.x*128 + wid*32;
  int arow = lane & 15, kgrp = lane >> 4;
  long r0 = row0 + arow;      if (r0 > (long)N-1) r0 = N-1;
  long r1 = row0 + 16 + arow; if (r1 > (long)N-1) r1 = N-1;
  const unsigned short* ap0 = X + (size_t)r0*XDIM + FF + kgrp*8;
  const unsigned short* ap1 = X + (size_t)r1*XDIM + FF + kgrp*8;
  const unsigned short* bptr = WfH + lane*8;
  f32x4 acc00={0.f,0.f,0.f,0.f}, acc01=acc00, acc02=acc00, acc03=acc00;
  f32x4 acc10=acc00, acc11=acc00, acc12=acc00, acc13=acc00;
  for (int kb=0; kb<nkb2; ++kb){
    bf16x8 a0 = *(const bf16x8*)(ap0 + (size_t)kb*32);
    bf16x8 a1 = *(const bf16x8*)(ap1 + (size_t)kb*32);
    const unsigned short* bp = bptr + (size_t)kb*2048;
    bf16x8 b0=*(const bf16x8*)bp, b1=*(const bf16x8*)(bp+512),
           b2=*(const bf16x8*)(bp+1024), b3=*(const bf16x8*)(bp+1536);
    acc00=__builtin_amdgcn_mfma_f32_16x16x32_bf16(a0,b0,acc00,0,0,0);
    acc10=__builtin_amdgcn_mfma_f32_16x16x32_bf16(a1,b0,acc10,0,0,0);
    acc01=__builtin_amdgcn_mfma_f32_16x16x32_bf16(a0,b1,acc01,0,0,0);
    acc11=__builtin_amdgcn_mfma_f32_16x16x32_bf16(a1,b1,acc11,0,0,0);
    acc02=__builtin_amdgcn_mfma_f32_16x16x32_bf16(a0,b2,acc02,0,0,0);
    acc12=__builtin_amdgcn_mfma_f32_16x16x32_bf16(a1,b2,acc12,0,0,0);
    acc03=__builtin_amdgcn_mfma_f32_16x16x32_bf16(a0,b3,acc03,0,0,0);
    acc13=__builtin_amdgcn_mfma_f32_16x16x32_bf16(a1,b3,acc13,0,0,0);
  }
  for (int j=0;j<4;++j){
    long rr = row0 + kgrp*4 + j;
    if (rr < N){
      float dv = dinv[rr];
      const unsigned short* pp = part + (size_t)rr*64 + arow;
      unsigned short* lp = lin + (size_t)rr*64 + arow;
      lp[0]  = f2bf((acc00[j]+bf2f(pp[0]))*dv);
      lp[16] = f2bf((acc01[j]+bf2f(pp[16]))*dv);
      lp[32] = f2bf((acc02[j]+bf2f(pp[32]))*dv);
      lp[48] = f2bf((acc03[j]+bf2f(pp[48]))*dv);
    }
    long rr1 = rr + 16;
    if (rr1 < N){
      float dv = dinv[rr1];
      const unsigned short* pp = part + (size_t)rr1*64 + arow;
      unsigned short* lp = lin + (size_t)rr1*64 + arow;
      lp[0]  = f2bf((acc10[j]+bf2f(pp[0]))*dv);
      lp[16] = f2bf((acc11[j]+bf2f(pp[16]))*dv);
      lp[32] = f2bf((acc12[j]+bf2f(pp[32]))*dv);
      lp[48] = f2bf((acc13[j]+bf2f(pp[48]))*dv);
    }
  }
}

// ---- aggregate (R5/R9-proven): 1 wave/node; lane=(sub 0..3, fq 0..15); uint2 gathers ----
__global__ void __launch_bounds__(256) k_agg(const unsigned short* __restrict__ lin,
                                             const int* __restrict__ offsS,
                                             const int* __restrict__ offsE,
                                             const int* __restrict__ esrc,
                                             const float* __restrict__ dinv,
                                             const float* __restrict__ bias,
                                             unsigned short* __restrict__ X,
                                             int colbase, int N){
  int lane = threadIdx.x & 63, wid = threadIdx.x >> 6;
  int n = blockIdx.x*4 + wid;
  if (n >= N) return;
  int sub = lane >> 4;
  int fq  = lane & 15;
  const unsigned short* lq = lin + fq*4;
  float a0=0.f, a1=0.f, a2=0.f, a3=0.f;
  int s = offsS[n], e = offsE[n];
  int base = s;
  for (; base + 32 <= e; base += 32){
    #pragma unroll
    for (int k=0;k<8;++k){
      int sx = esrc[base + 4*k + sub];
      uint2 v = *(const uint2*)(lq + (size_t)sx*64);
      a0 += u2f(v.x<<16); a1 += u2f(v.x&0xffff0000u);
      a2 += u2f(v.y<<16); a3 += u2f(v.y&0xffff0000u);
    }
  }
  if (base < e){
    int rem = e - base;
    if (rem > 16){
      #pragma unroll
      for (int k=0;k<8;++k){
        int idx = 4*k + sub;
        int sx = esrc[base + idx];
        sx = (idx < rem) ? sx : (int)N;
        uint2 v = *(const uint2*)(lq + (size_t)sx*64);
        a0 += u2f(v.x<<16); a1 += u2f(v.x&0xffff0000u);
        a2 += u2f(v.y<<16); a3 += u2f(v.y&0xffff0000u);
      }
    } else {
      #pragma unroll
      for (int k=0;k<4;++k){
        int idx = 4*k + sub;
        int sx = esrc[base + idx];
        sx = (idx < rem) ? sx : (int)N;
        uint2 v = *(const uint2*)(lq + (size_t)sx*64);
        a0 += u2f(v.x<<16); a1 += u2f(v.x&0xffff0000u);
        a2 += u2f(v.y<<16); a3 += u2f(v.y&0xffff0000u);
      }
    }
  }
  a0 += __shfl_xor(a0,16,64); a0 += __shfl_xor(a0,32,64);
  a1 += __shfl_xor(a1,16,64); a1 += __shfl_xor(a1,32,64);
  a2 += __shfl_xor(a2,16,64); a2 += __shfl_xor(a2,32,64);
  a3 += __shfl_xor(a3,16,64); a3 += __shfl_xor(a3,32,64);
  uint2 vs = *(const uint2*)(lq + (size_t)n*64);
  a0 += u2f(vs.x<<16); a1 += u2f(vs.x&0xffff0000u);
  a2 += u2f(vs.y<<16); a3 += u2f(vs.y&0xffff0000u);
  float dv = dinv[n];
  float4 b4 = *(const float4*)(bias + fq*4);
  float h0 = fmaxf(a0*dv + b4.x, 0.f);
  float h1 = fmaxf(a1*dv + b4.y, 0.f);
  float h2 = fmaxf(a2*dv + b4.z, 0.f);
  float h3 = fmaxf(a3*dv + b4.w, 0.f);
  if (sub == 0){
    ushort4 o; o.x=f2bf(h0); o.y=f2bf(h1); o.z=f2bf(h2); o.w=f2bf(h3);
    *(ushort4*)(X + (size_t)n*XDIM + colbase + fq*4) = o;
  }
}

// ---- final: logits = pF + X[:,512:896] @ WfLinH + blin, log_softmax ----
__global__ void __launch_bounds__(256) k_final(const unsigned short* __restrict__ X,
                                               const unsigned short* __restrict__ Wf,
                                               const float* __restrict__ pF,
                                               const float* __restrict__ blin,
                                               float* __restrict__ out, int N){
  int lane=threadIdx.x&63, wid=threadIdx.x>>6;
  long row0=(long)blockIdx.x*64 + wid*16;
  int c0=lane&15, g=lane>>4;
  long r=row0+c0; if (r > (long)N-1) r = N-1;
  const unsigned short* aptr = X + (size_t)r*XDIM + FF + g*8;
  const unsigned short* bptr = Wf + lane*8;
  f32x4 acc0={0.f,0.f,0.f,0.f}, acc1=acc0, acc2=acc0;
  const int nkb = (XDIM-FF)/32;  // 12
  for (int kb=0;kb<nkb;++kb){
    bf16x8 a=*(const bf16x8*)(aptr+(size_t)kb*32);
    const unsigned short* bp = bptr + (size_t)kb*1536;
    bf16x8 b0=*(const bf16x8*)bp, b1=*(const bf16x8*)(bp+512), b2=*(const bf16x8*)(bp+1024);
    acc0=__builtin_amdgcn_mfma_f32_16x16x32_bf16(a,b0,acc0,0,0,0);
    acc1=__builtin_amdgcn_mfma_f32_16x16x32_bf16(a,b1,acc1,0,0,0);
    acc2=__builtin_amdgcn_mfma_f32_16x16x32_bf16(a,b2,acc2,0,0,0);
  }
  float bl0 = blin[c0], bl1 = blin[16+c0];
  bool v2ok = (c0 < 8);
  float bl2 = v2ok ? blin[32+c0] : 0.f;
  for (int j=0;j<4;++j){
    long rr = row0 + g*4 + j;
    long rrc = rr < N ? rr : (long)N-1;
    const float* pp = pF + (size_t)rrc*CC;
    float v0 = acc0[j]+bl0+pp[c0], v1 = acc1[j]+bl1+pp[16+c0];
    float v2 = v2ok ? (acc2[j]+bl2+pp[32+c0]) : -1e30f;
    float m = fmaxf(fmaxf(v0,v1),v2);
    m = fmaxf(m, __shfl_xor(m,1,64));
    m = fmaxf(m, __shfl_xor(m,2,64));
    m = fmaxf(m, __shfl_xor(m,4,64));
    m = fmaxf(m, __shfl_xor(m,8,64));
    float sEx = expf(v0-m)+expf(v1-m)+(v2ok?expf(v2-m):0.f);
    sEx += __shfl_xor(sEx,1,64);
    sEx += __shfl_xor(sEx,2,64);
    sEx += __shfl_xor(sEx,4,64);
    sEx += __shfl_xor(sEx,8,64);
    float lse = m + logf(sEx);
    if (rr < N){
      out[(size_t)rr*CC + c0]      = v0 - lse;
      out[(size_t)rr*CC + 16 + c0] = v1 - lse;
      if (v2ok) out[(size_t)rr*CC + 32 + c0] = v2 - lse;
    }
  }
}

extern "C" void kernel_launch(void* const* d_in, const int* in_sizes, int n_in,
                              void* d_out, int out_size, void* d_ws, size_t ws_size,
                              hipStream_t stream){
  const float* x = (const float*)d_in[0];
  const int* ei = (const int*)d_in[1];
  const float* Wl[LL]; const float* bl[LL];
  for (int i=0;i<LL;i++){ Wl[i]=(const float*)d_in[2+2*i]; bl[i]=(const float*)d_in[3+2*i]; }
  const float* Wlin = (const float*)d_in[2+2*LL];
  const float* blin = (const float*)d_in[3+2*LL];
  float* out = (float*)d_out;
  const int N = in_sizes[0]/FF;
  const int E = in_sizes[1]/2;
  const int NB = (N+CBSZ-1)/CBSZ;

  char* p = (char*)d_ws;
  auto alloc = [&](size_t bb)->char*{ char* r=p; p += (bb+255)&~(size_t)255; return r; };
  unsigned short* X   = (unsigned short*)alloc((size_t)N*XDIM*2);
  unsigned short* lin = (unsigned short*)alloc((size_t)(N+1)*64*2);  // +1 zero row
  unsigned* tmp = (unsigned*)lin;  // alias: tmp dead before gbig writes lin
  unsigned short* WfBig  = (unsigned short*)alloc((size_t)16*27*512*2);
  unsigned short* WfH[LL];   // index 1..5
  for (int i=1;i<LL;i++) WfH[i]=(unsigned short*)alloc((size_t)(2*i)*4*512*2);
  unsigned short* WfLinH = (unsigned short*)alloc((size_t)12*3*512*2);
  unsigned short* part[LL];  // index 1..5
  for (int i=1;i<LL;i++) part[i]=(unsigned short*)alloc((size_t)N*64*2);
  float* pF    = (float*)alloc((size_t)N*CC*4);
  float* dinv  = (float*)alloc((size_t)N*4);
  int* offsS   = (int*)alloc((size_t)N*4);
  int* offsE   = (int*)alloc((size_t)N*4);
  int* bcur    = (int*)alloc((size_t)NB*4);
  int* esrc    = (int*)alloc(((size_t)NB*SLACK+64)*4);

  PrepP P;
  P.x=x; P.ei=ei; P.X=X; P.lin=lin; P.bcur=bcur; P.tmp=tmp;
  int off=0, sg=0;
  // big segments: 6 layer W prefixes + Wlin prefix -> WfBig [kb][27][512]
  for (int i=0;i<LL;i++){
    P.W[sg]=Wl[i]; P.dst[sg]=WfBig; P.nt[sg]=4; P.nc[sg]=HH;
    P.tst[sg]=27; P.tbs[sg]=4*i; P.kbase[sg]=0;
    P.off[sg]=off; off += 16*4*512; ++sg;
  }
  P.W[sg]=Wlin; P.dst[sg]=WfBig; P.nt[sg]=3; P.nc[sg]=CC;
  P.tst[sg]=27; P.tbs[sg]=24; P.kbase[sg]=0;
  P.off[sg]=off; off += 16*3*512; ++sg;
  // H segments for layers 1..5
  for (int i=1;i<LL;i++){
    P.W[sg]=Wl[i]; P.dst[sg]=WfH[i]; P.nt[sg]=4; P.nc[sg]=HH;
    P.tst[sg]=4; P.tbs[sg]=0; P.kbase[sg]=FF;
    P.off[sg]=off; off += (2*i)*4*512; ++sg;
  }
  // Wlin H segment
  P.W[sg]=Wlin; P.dst[sg]=WfLinH; P.nt[sg]=3; P.nc[sg]=CC;
  P.tst[sg]=3; P.tbs[sg]=0; P.kbase[sg]=FF;
  P.off[sg]=off; off += 12*3*512; ++sg;
  P.off[sg]=off;
  P.N=N; P.E=E; P.CH=(E+255)/256; P.NB=NB; P.WB=(off+255)/256;
  int XB=(N*(FF/4)+255)/256;

  hipMemsetAsync(bcur, 0, (size_t)NB*4, stream);
  k_prep <<<256 + P.WB + XB, 256, 0, stream>>>(P);
  k_build<<<NB, 1024, 0, stream>>>(tmp, bcur, offsS, offsE, dinv, esrc, N);

  GBP G;
  G.X=X; G.WfBig=WfBig; G.dinv=dinv;
  G.pl[0]=lin;
  for (int i=1;i<LL;i++) G.pl[i]=part[i];
  G.pF=pF; G.N=N;
  k_gbig<<<(N+31)/32, 256, 0, stream>>>(G);

  int gb = (N+127)/128;
  int ab = (N+3)/4;
  for (int i=0;i<LL;i++){
    if (i>0) k_gemmH<<<gb,256,0,stream>>>(X, WfH[i], part[i], dinv, lin, N, 2*i);
    k_agg<<<ab,256,0,stream>>>(lin, offsS, offsE, esrc, dinv, bl[i], X, FF+HH*i, N);
  }
  k_final<<<(N+63)/64,256,0,stream>>>(X, WfLinH, pF, blin, out, N);
}

// Round 14
// 591.523 us; speedup vs baseline: 1.6492x; 1.0842x over previous
//
#include <hip/hip_runtime.h>
#include <hip/hip_bf16.h>

#define HH 64
#define XDIM 896
#define FF 512
#define LL 6
#define CC 40
#define CBSZ 512          // nodes per coarse bucket
#define SLACK 10240       // slots per bucket region
#define NSEG 13

typedef __bf16 bf16x8 __attribute__((ext_vector_type(8)));
typedef float f32x4 __attribute__((ext_vector_type(4)));

__device__ __forceinline__ unsigned short f2bf(float f){
  union{float f; unsigned int u;} v; v.f=f; unsigned int u=v.u;
  return (unsigned short)((u + 0x7fffu + ((u>>16)&1u))>>16);
}
__device__ __forceinline__ float bf2f(unsigned short u){
  union{unsigned int u; float f;} v; v.u = ((unsigned int)u)<<16; return v.f;
}
__device__ __forceinline__ float u2f(unsigned u){
  union{unsigned u; float f;} v; v.u=u; return v.f;
}

// ---- fused prep: [0,256) edge-partition | [256,256+WB) wfrag | rest xcast ----
struct PrepP {
  const float* x; const int* ei;
  unsigned short* X; unsigned short* lin;
  int* bcur; unsigned* tmp;
  const float* W[NSEG]; unsigned short* dst[NSEG];
  int nt[NSEG], nc[NSEG], tst[NSEG], tbs[NSEG], kbase[NSEG];
  int off[NSEG+1];
  int N, E, CH, NB, WB;
};

__global__ void __launch_bounds__(256) k_prep(PrepP P){
  __shared__ int hist[256];
  __shared__ int run[256];
  int t=threadIdx.x, b=blockIdx.x;
  if (b < 256){
    int E=P.E;
    int lo=b*P.CH, hi=lo+P.CH; if (hi>E) hi=E;
    for (int i=t;i<P.NB;i+=256) hist[i]=0;
    __syncthreads();
    for (int i=lo+t;i<hi;i+=256) atomicAdd(&hist[P.ei[E+i]>>9], 1);
    __syncthreads();
    for (int i=t;i<P.NB;i+=256) run[i]=i*SLACK+atomicAdd(&P.bcur[i], hist[i]);
    __syncthreads();
    for (int i=lo+t;i<hi;i+=256){
      int r=P.ei[i], c=P.ei[E+i];
      int pos=atomicAdd(&run[c>>9],1);
      P.tmp[pos]=((unsigned)r<<9)|(unsigned)(c&(CBSZ-1));
    }
  } else if (b < 256+P.WB){
    int idx=(b-256)*256+t;
    if (idx < P.off[NSEG]){
      int seg=0;
      while (idx>=P.off[seg+1]) ++seg;
      int li=idx-P.off[seg];
      int j=li&7, ln=(li>>3)&63, rem2=li>>9;
      int ntile=P.nt[seg], ncols=P.nc[seg];
      int nt_=rem2%ntile, kb=rem2/ntile;
      int k=P.kbase[seg]+kb*32+(ln>>4)*8+j;
      int c=nt_*16+(ln&15);
      float v=(c<ncols)? P.W[seg][(size_t)k*ncols+c] : 0.f;
      int di = ((kb*P.tst[seg] + P.tbs[seg] + nt_)*64 + ln)*8 + j;
      P.dst[seg][di]=f2bf(v);
    }
  } else {
    int i=(b-256-P.WB)*256+t;
    if (i<32) ((unsigned*)(P.lin+(size_t)P.N*64))[i]=0u;
    int total=P.N*(FF/4);
    if (i<total){
      int row=i/(FF/4), c4=(i%(FF/4))*4;
      float4 v=*(const float4*)(P.x+(size_t)row*FF+c4);
      ushort4 o; o.x=f2bf(v.x); o.y=f2bf(v.y); o.z=f2bf(v.z); o.w=f2bf(v.w);
      *(ushort4*)(P.X+(size_t)row*XDIM+c4)=o;
    }
  }
}

// ---- per-bucket: LDS count + scan -> offs/dinv; LDS-cursor scatter -> esrc ----
__global__ void __launch_bounds__(1024) k_build(const unsigned* __restrict__ tmp,
                                                const int* __restrict__ bcur,
                                                int* __restrict__ offsS, int* __restrict__ offsE,
                                                float* __restrict__ dinv,
                                                int* __restrict__ esrc, int N){
  __shared__ int cnt[CBSZ];
  __shared__ int run[CBSZ];
  int t=threadIdx.x, b=blockIdx.x;
  int n0=b*CBSZ;
  int nloc=N-n0; if (nloc>CBSZ) nloc=CBSZ;
  int wbase=b*SLACK;
  int wend=wbase + bcur[b];
  if (t<CBSZ) cnt[t]=0;
  __syncthreads();
  for (int i=wbase+t; i<wend; i+=1024) atomicAdd(&cnt[tmp[i]&(CBSZ-1u)],1);
  __syncthreads();
  int v = (t<CBSZ)? cnt[t] : 0;
  if (t<CBSZ) run[t]=v;
  __syncthreads();
  for (int o=1;o<CBSZ;o<<=1){
    int xx = (t<CBSZ && t>=o)? run[t-o] : 0;
    __syncthreads();
    if (t<CBSZ) run[t]+=xx;
    __syncthreads();
  }
  if (t<nloc){
    int s = wbase + (run[t]-v);
    offsS[n0+t]=s;
    offsE[n0+t]=s+v;
    dinv[n0+t]=rsqrtf((float)(v+1));
    run[t]=s;
  }
  __syncthreads();
  for (int i=wbase+t; i<wend; i+=1024){
    unsigned vv=tmp[i];
    int pos=atomicAdd(&run[vv&(CBSZ-1u)],1);
    esrc[pos]=(int)(vv>>9);
  }
}

// ---- big pass v3: 32 rows x 7 tiles per wave (4 waves cover 28 slots; slot 27 = pad) ----
struct GBP {
  const unsigned short* X; const unsigned short* WfBig;
  const float* dinv;
  unsigned short* pl[6];   // pl[0] = lin (dinv applied), 1..5 = raw bf16 partials
  float* pF;               // [N,40] fp32 logits partial
  int N;
};

__global__ void __launch_bounds__(256) k_gbig(GBP P){
  int t=threadIdx.x, lane=t&63, wid=t>>6;
  int tb = wid*7;              // tiles [tb, tb+7); tile 27 is pad (write-skipped)
  long row0 = (long)blockIdx.x*32;
  int arow=lane&15, kgrp=lane>>4;
  long r0=row0+arow;    if (r0>(long)P.N-1) r0=P.N-1;
  long r1=row0+16+arow; if (r1>(long)P.N-1) r1=P.N-1;
  const unsigned short* ap0 = P.X + (size_t)r0*XDIM + kgrp*8;
  const unsigned short* ap1 = P.X + (size_t)r1*XDIM + kgrp*8;
  const unsigned short* bbase = P.WfBig + (size_t)tb*512 + lane*8;
  f32x4 acc0[7], acc1[7];
  #pragma unroll
  for (int i=0;i<7;i++){ f32x4 z={0.f,0.f,0.f,0.f}; acc0[i]=z; acc1[i]=z; }
  for (int kb=0;kb<16;++kb){
    bf16x8 a0=*(const bf16x8*)(ap0+(size_t)kb*32);
    bf16x8 a1=*(const bf16x8*)(ap1+(size_t)kb*32);
    const unsigned short* bp = bbase + (size_t)kb*28*512;
    #pragma unroll
    for (int tt=0;tt<7;++tt){
      bf16x8 b=*(const bf16x8*)(bp + tt*512);
      acc0[tt]=__builtin_amdgcn_mfma_f32_16x16x32_bf16(a0,b,acc0[tt],0,0,0);
      acc1[tt]=__builtin_amdgcn_mfma_f32_16x16x32_bf16(a1,b,acc1[tt],0,0,0);
    }
  }
  #pragma unroll
  for (int tt=0;tt<7;++tt){
    int tg = tb+tt;
    if (tg >= 27) continue;    // pad slot
    #pragma unroll
    for (int j=0;j<4;++j){
      long rr=row0+kgrp*4+j;
      long rr1=rr+16;
      if (tg<24){
        int li=tg>>2, tloc=tg&3;
        if (rr<P.N){
          float s = (li==0) ? P.dinv[rr] : 1.f;
          P.pl[li][(size_t)rr*64 + tloc*16 + arow] = f2bf(acc0[tt][j]*s);
        }
        if (rr1<P.N){
          float s = (li==0) ? P.dinv[rr1] : 1.f;
          P.pl[li][(size_t)rr1*64 + tloc*16 + arow] = f2bf(acc1[tt][j]*s);
        }
      } else {
        int c=(tg-24)*16+arow;
        if (c<CC){
          if (rr<P.N)  P.pF[(size_t)rr*CC+c]=acc0[tt][j];
          if (rr1<P.N) P.pF[(size_t)rr1*CC+c]=acc1[tt][j];
        }
      }
    }
  }
}

// ---- layer-i gemm over H cols only: lin = dinv*(partial + X[:,512:512+64i] @ WfH) ----
__global__ void __launch_bounds__(256) k_gemmH(const unsigned short* __restrict__ X,
                                               const unsigned short* __restrict__ WfH,
                                               const unsigned short* __restrict__ part,
                                               const float* __restrict__ dinv,
                                               unsigned short* __restrict__ lin,
                                               int N, int nkb2){
  int lane = threadIdx.x & 63, wid = threadIdx.x >> 6;
  long row0 = (long)blockIdx.x*128 + wid*32;
  int arow = lane & 15, kgrp = lane >> 4;
  long r0 = row0 + arow;      if (r0 > (long)N-1) r0 = N-1;
  long r1 = row0 + 16 + arow; if (r1 > (long)N-1) r1 = N-1;
  const unsigned short* ap0 = X + (size_t)r0*XDIM + FF + kgrp*8;
  const unsigned short* ap1 = X + (size_t)r1*XDIM + FF + kgrp*8;
  const unsigned short* bptr = WfH + lane*8;
  f32x4 acc00={0.f,0.f,0.f,0.f}, acc01=acc00, acc02=acc00, acc03=acc00;
  f32x4 acc10=acc00, acc11=acc00, acc12=acc00, acc13=acc00;
  for (int kb=0; kb<nkb2; ++kb){
    bf16x8 a0 = *(const bf16x8*)(ap0 + (size_t)kb*32);
    bf16x8 a1 = *(const bf16x8*)(ap1 + (size_t)kb*32);
    const unsigned short* bp = bptr + (size_t)kb*2048;
    bf16x8 b0=*(const bf16x8*)bp, b1=*(const bf16x8*)(bp+512),
           b2=*(const bf16x8*)(bp+1024), b3=*(const bf16x8*)(bp+1536);
    acc00=__builtin_amdgcn_mfma_f32_16x16x32_bf16(a0,b0,acc00,0,0,0);
    acc10=__builtin_amdgcn_mfma_f32_16x16x32_bf16(a1,b0,acc10,0,0,0);
    acc01=__builtin_amdgcn_mfma_f32_16x16x32_bf16(a0,b1,acc01,0,0,0);
    acc11=__builtin_amdgcn_mfma_f32_16x16x32_bf16(a1,b1,acc11,0,0,0);
    acc02=__builtin_amdgcn_mfma_f32_16x16x32_bf16(a0,b2,acc02,0,0,0);
    acc12=__builtin_amdgcn_mfma_f32_16x16x32_bf16(a1,b2,acc12,0,0,0);
    acc03=__builtin_amdgcn_mfma_f32_16x16x32_bf16(a0,b3,acc03,0,0,0);
    acc13=__builtin_amdgcn_mfma_f32_16x16x32_bf16(a1,b3,acc13,0,0,0);
  }
  for (int j=0;j<4;++j){
    long rr = row0 + kgrp*4 + j;
    if (rr < N){
      float dv = dinv[rr];
      const unsigned short* pp = part + (size_t)rr*64 + arow;
      unsigned short* lp = lin + (size_t)rr*64 + arow;
      lp[0]  = f2bf((acc00[j]+bf2f(pp[0]))*dv);
      lp[16] = f2bf((acc01[j]+bf2f(pp[16]))*dv);
      lp[32] = f2bf((acc02[j]+bf2f(pp[32]))*dv);
      lp[48] = f2bf((acc03[j]+bf2f(pp[48]))*dv);
    }
    long rr1 = rr + 16;
    if (rr1 < N){
      float dv = dinv[rr1];
      const unsigned short* pp = part + (size_t)rr1*64 + arow;
      unsigned short* lp = lin + (size_t)rr1*64 + arow;
      lp[0]  = f2bf((acc10[j]+bf2f(pp[0]))*dv);
      lp[16] = f2bf((acc11[j]+bf2f(pp[16]))*dv);
      lp[32] = f2bf((acc12[j]+bf2f(pp[32]))*dv);
      lp[48] = f2bf((acc13[j]+bf2f(pp[48]))*dv);
    }
  }
}

// ---- aggregate (R5/R9-proven): 1 wave/node; lane=(sub 0..3, fq 0..15); uint2 gathers ----
__global__ void __launch_bounds__(256) k_agg(const unsigned short* __restrict__ lin,
                                             const int* __restrict__ offsS,
                                             const int* __restrict__ offsE,
                                             const int* __restrict__ esrc,
                                             const float* __restrict__ dinv,
                                             const float* __restrict__ bias,
                                             unsigned short* __restrict__ X,
                                             int colbase, int N){
  int lane = threadIdx.x & 63, wid = threadIdx.x >> 6;
  int n = blockIdx.x*4 + wid;
  if (n >= N) return;
  int sub = lane >> 4;
  int fq  = lane & 15;
  const unsigned short* lq = lin + fq*4;
  float a0=0.f, a1=0.f, a2=0.f, a3=0.f;
  int s = offsS[n], e = offsE[n];
  int base = s;
  for (; base + 32 <= e; base += 32){
    #pragma unroll
    for (int k=0;k<8;++k){
      int sx = esrc[base + 4*k + sub];
      uint2 v = *(const uint2*)(lq + (size_t)sx*64);
      a0 += u2f(v.x<<16); a1 += u2f(v.x&0xffff0000u);
      a2 += u2f(v.y<<16); a3 += u2f(v.y&0xffff0000u);
    }
  }
  if (base < e){
    int rem = e - base;
    if (rem > 16){
      #pragma unroll
      for (int k=0;k<8;++k){
        int idx = 4*k + sub;
        int sx = esrc[base + idx];
        sx = (idx < rem) ? sx : (int)N;
        uint2 v = *(const uint2*)(lq + (size_t)sx*64);
        a0 += u2f(v.x<<16); a1 += u2f(v.x&0xffff0000u);
        a2 += u2f(v.y<<16); a3 += u2f(v.y&0xffff0000u);
      }
    } else {
      #pragma unroll
      for (int k=0;k<4;++k){
        int idx = 4*k + sub;
        int sx = esrc[base + idx];
        sx = (idx < rem) ? sx : (int)N;
        uint2 v = *(const uint2*)(lq + (size_t)sx*64);
        a0 += u2f(v.x<<16); a1 += u2f(v.x&0xffff0000u);
        a2 += u2f(v.y<<16); a3 += u2f(v.y&0xffff0000u);
      }
    }
  }
  a0 += __shfl_xor(a0,16,64); a0 += __shfl_xor(a0,32,64);
  a1 += __shfl_xor(a1,16,64); a1 += __shfl_xor(a1,32,64);
  a2 += __shfl_xor(a2,16,64); a2 += __shfl_xor(a2,32,64);
  a3 += __shfl_xor(a3,16,64); a3 += __shfl_xor(a3,32,64);
  uint2 vs = *(const uint2*)(lq + (size_t)n*64);
  a0 += u2f(vs.x<<16); a1 += u2f(vs.x&0xffff0000u);
  a2 += u2f(vs.y<<16); a3 += u2f(vs.y&0xffff0000u);
  float dv = dinv[n];
  float4 b4 = *(const float4*)(bias + fq*4);
  float h0 = fmaxf(a0*dv + b4.x, 0.f);
  float h1 = fmaxf(a1*dv + b4.y, 0.f);
  float h2 = fmaxf(a2*dv + b4.z, 0.f);
  float h3 = fmaxf(a3*dv + b4.w, 0.f);
  if (sub == 0){
    ushort4 o; o.x=f2bf(h0); o.y=f2bf(h1); o.z=f2bf(h2); o.w=f2bf(h3);
    *(ushort4*)(X + (size_t)n*XDIM + colbase + fq*4) = o;
  }
}

// ---- final: logits = pF + X[:,512:896] @ WfLinH + blin, log_softmax ----
__global__ void __launch_bounds__(256) k_final(const unsigned short* __restrict__ X,
                                               const unsigned short* __restrict__ Wf,
                                               const float* __restrict__ pF,
                                               const float* __restrict__ blin,
                                               float* __restrict__ out, int N){
  int lane=threadIdx.x&63, wid=threadIdx.x>>6;
  long row0=(long)blockIdx.x*64 + wid*16;
  int c0=lane&15, g=lane>>4;
  long r=row0+c0; if (r > (long)N-1) r = N-1;
  const unsigned short* aptr = X + (size_t)r*XDIM + FF + g*8;
  const unsigned short* bptr = Wf + lane*8;
  f32x4 acc0={0.f,0.f,0.f,0.f}, acc1=acc0, acc2=acc0;
  const int nkb = (XDIM-FF)/32;  // 12
  for (int kb=0;kb<nkb;++kb){
    bf16x8 a=*(const bf16x8*)(aptr+(size_t)kb*32);
    const unsigned short* bp = bptr + (size_t)kb*1536;
    bf16x8 b0=*(const bf16x8*)bp, b1=*(const bf16x8*)(bp+512), b2=*(const bf16x8*)(bp+1024);
    acc0=__builtin_amdgcn_mfma_f32_16x16x32_bf16(a,b0,acc0,0,0,0);
    acc1=__builtin_amdgcn_mfma_f32_16x16x32_bf16(a,b1,acc1,0,0,0);
    acc2=__builtin_amdgcn_mfma_f32_16x16x32_bf16(a,b2,acc2,0,0,0);
  }
  float bl0 = blin[c0], bl1 = blin[16+c0];
  bool v2ok = (c0 < 8);
  float bl2 = v2ok ? blin[32+c0] : 0.f;
  for (int j=0;j<4;++j){
    long rr = row0 + g*4 + j;
    long rrc = rr < N ? rr : (long)N-1;
    const float* pp = pF + (size_t)rrc*CC;
    float v0 = acc0[j]+bl0+pp[c0], v1 = acc1[j]+bl1+pp[16+c0];
    float v2 = v2ok ? (acc2[j]+bl2+pp[32+c0]) : -1e30f;
    float m = fmaxf(fmaxf(v0,v1),v2);
    m = fmaxf(m, __shfl_xor(m,1,64));
    m = fmaxf(m, __shfl_xor(m,2,64));
    m = fmaxf(m, __shfl_xor(m,4,64));
    m = fmaxf(m, __shfl_xor(m,8,64));
    float sEx = expf(v0-m)+expf(v1-m)+(v2ok?expf(v2-m):0.f);
    sEx += __shfl_xor(sEx,1,64);
    sEx += __shfl_xor(sEx,2,64);
    sEx += __shfl_xor(sEx,4,64);
    sEx += __shfl_xor(sEx,8,64);
    float lse = m + logf(sEx);
    if (rr < N){
      out[(size_t)rr*CC + c0]      = v0 - lse;
      out[(size_t)rr*CC + 16 + c0] = v1 - lse;
      if (v2ok) out[(size_t)rr*CC + 32 + c0] = v2 - lse;
    }
  }
}

extern "C" void kernel_launch(void* const* d_in, const int* in_sizes, int n_in,
                              void* d_out, int out_size, void* d_ws, size_t ws_size,
                              hipStream_t stream){
  const float* x = (const float*)d_in[0];
  const int* ei = (const int*)d_in[1];
  const float* Wl[LL]; const float* bl[LL];
  for (int i=0;i<LL;i++){ Wl[i]=(const float*)d_in[2+2*i]; bl[i]=(const float*)d_in[3+2*i]; }
  const float* Wlin = (const float*)d_in[2+2*LL];
  const float* blin = (const float*)d_in[3+2*LL];
  float* out = (float*)d_out;
  const int N = in_sizes[0]/FF;
  const int E = in_sizes[1]/2;
  const int NB = (N+CBSZ-1)/CBSZ;

  char* p = (char*)d_ws;
  auto alloc = [&](size_t bb)->char*{ char* r=p; p += (bb+255)&~(size_t)255; return r; };
  unsigned short* X   = (unsigned short*)alloc((size_t)N*XDIM*2);
  unsigned short* lin = (unsigned short*)alloc((size_t)(N+1)*64*2);  // +1 zero row
  unsigned* tmp = (unsigned*)lin;  // alias: tmp dead before gbig writes lin
  unsigned short* WfBig  = (unsigned short*)alloc((size_t)16*28*512*2);  // 28-tile stride (27 used + pad)
  unsigned short* WfH[LL];   // index 1..5
  for (int i=1;i<LL;i++) WfH[i]=(unsigned short*)alloc((size_t)(2*i)*4*512*2);
  unsigned short* WfLinH = (unsigned short*)alloc((size_t)12*3*512*2);
  unsigned short* part[LL];  // index 1..5
  for (int i=1;i<LL;i++) part[i]=(unsigned short*)alloc((size_t)N*64*2);
  float* pF    = (float*)alloc((size_t)N*CC*4);
  float* dinv  = (float*)alloc((size_t)N*4);
  int* offsS   = (int*)alloc((size_t)N*4);
  int* offsE   = (int*)alloc((size_t)N*4);
  int* bcur    = (int*)alloc((size_t)NB*4);
  int* esrc    = (int*)alloc(((size_t)NB*SLACK+64)*4);

  PrepP P;
  P.x=x; P.ei=ei; P.X=X; P.lin=lin; P.bcur=bcur; P.tmp=tmp;
  int off=0, sg=0;
  // big segments: 6 layer W prefixes + Wlin prefix -> WfBig [kb][28][512] (slot 27 pad)
  for (int i=0;i<LL;i++){
    P.W[sg]=Wl[i]; P.dst[sg]=WfBig; P.nt[sg]=4; P.nc[sg]=HH;
    P.tst[sg]=28; P.tbs[sg]=4*i; P.kbase[sg]=0;
    P.off[sg]=off; off += 16*4*512; ++sg;
  }
  P.W[sg]=Wlin; P.dst[sg]=WfBig; P.nt[sg]=3; P.nc[sg]=CC;
  P.tst[sg]=28; P.tbs[sg]=24; P.kbase[sg]=0;
  P.off[sg]=off; off += 16*3*512; ++sg;
  // H segments for layers 1..5
  for (int i=1;i<LL;i++){
    P.W[sg]=Wl[i]; P.dst[sg]=WfH[i]; P.nt[sg]=4; P.nc[sg]=HH;
    P.tst[sg]=4; P.tbs[sg]=0; P.kbase[sg]=FF;
    P.off[sg]=off; off += (2*i)*4*512; ++sg;
  }
  // Wlin H segment
  P.W[sg]=Wlin; P.dst[sg]=WfLinH; P.nt[sg]=3; P.nc[sg]=CC;
  P.tst[sg]=3; P.tbs[sg]=0; P.kbase[sg]=FF;
  P.off[sg]=off; off += 12*3*512; ++sg;
  P.off[sg]=off;
  P.N=N; P.E=E; P.CH=(E+255)/256; P.NB=NB; P.WB=(off+255)/256;
  int XB=(N*(FF/4)+255)/256;

  hipMemsetAsync(bcur, 0, (size_t)NB*4, stream);
  k_prep <<<256 + P.WB + XB, 256, 0, stream>>>(P);
  k_build<<<NB, 1024, 0, stream>>>(tmp, bcur, offsS, offsE, dinv, esrc, N);

  GBP G;
  G.X=X; G.WfBig=WfBig; G.dinv=dinv;
  G.pl[0]=lin;
  for (int i=1;i<LL;i++) G.pl[i]=part[i];
  G.pF=pF; G.N=N;
  k_gbig<<<(N+31)/32, 256, 0, stream>>>(G);

  int gb = (N+127)/128;
  int ab = (N+3)/4;
  for (int i=0;i<LL;i++){
    if (i>0) k_gemmH<<<gb,256,0,stream>>>(X, WfH[i], part[i], dinv, lin, N, 2*i);
    k_agg<<<ab,256,0,stream>>>(lin, offsS, offsE, esrc, dinv, bl[i], X, FF+HH*i, N);
  }
  k_final<<<(N+63)/64,256,0,stream>>>(X, WfLinH, pF, blin, out, N);
}